// Round 1
// baseline (289.981 us; speedup 1.0000x reference)
//
#include <hip/hip_runtime.h>

#define D 256
#define K 1024
#define NVEC 65536
#define ROWS 64       // rows per block
#define GROUPC 256    // codes per group (per-wave slice = 64)
#define NG (K / GROUPC)
#define NKB (D / 32)  // 8 k-steps of 32
#define MARGIN 0.5f   // ~7 sigma of bf16 coarse-distance error
#define MAXC 12
#define MAXP (ROWS * MAXC)

typedef __attribute__((ext_vector_type(8))) __bf16 bf16x8;
typedef __attribute__((ext_vector_type(4))) float floatx4;

__device__ inline unsigned short f2bf(float f) {  // RNE fp32->bf16
    unsigned int u = __float_as_uint(f);
    unsigned int r = u + 0x7fffu + ((u >> 16) & 1u);
    return (unsigned short)(r >> 16);
}
__device__ inline unsigned int fkey(float f) {    // order-preserving float->uint
    unsigned int b = __float_as_uint(f);
    return (b & 0x80000000u) ? ~b : (b | 0x80000000u);
}
__device__ inline float unfkey(unsigned int k) {
    unsigned int b = (k & 0x80000000u) ? (k & 0x7fffffffu) : ~k;
    return __uint_as_float(b);
}

// ws: cnorm fp32 [0,4KB) | lossAcc @4KB | doneCnt @4KB+4 | cbf bf16 @8KB (512KB)

// cbf layout: code c -> g=c>>8, w=(c>>6)&3, j=(c>>4)&3, col=c&15 ; k -> kb=k>>5,
// quad=(k>>3)&3, h=k&7.  16B seg index = S*64 + quad*16+col, S=((g*8+kb)*4+w)*4+j.
// In the k-loop, wave w / group g / kb / j reads seg S*64+lane => base + lane*16B.
__global__ void vq_prep(const float* __restrict__ cb, float* __restrict__ cnorm,
                        unsigned short* __restrict__ cbf, float* __restrict__ lossAcc,
                        unsigned int* __restrict__ doneCnt) {
    const int c = blockIdx.x;
    const int l = threadIdx.x;
    float4 v = *(const float4*)&cb[c * D + l * 4];
    float s = v.x * v.x + v.y * v.y + v.z * v.z + v.w * v.w;
#pragma unroll
    for (int off = 32; off > 0; off >>= 1) s += __shfl_down(s, off, 64);
    if (l == 0) cnorm[c] = s;
    const int g = c >> 8, w = (c >> 6) & 3, j = (c >> 4) & 3, col = c & 15;
    const int kb = l >> 3, quad = (l >> 1) & 3, h = (l & 1) * 4;
    const int S = ((g * 8 + kb) * 4 + w) * 4 + j;
    *(ushort4*)(cbf + (size_t)S * 512 + (quad * 16 + col) * 8 + h) =
        make_ushort4(f2bf(v.x), f2bf(v.y), f2bf(v.z), f2bf(v.w));
    if (c == 0 && l == 0) { *lossAcc = 0.f; *doneCnt = 0u; }
}

__global__ __launch_bounds__(256, 4) void vq_fused(
        const float* __restrict__ x, const float* __restrict__ cb,
        const unsigned short* __restrict__ cbf, const float* __restrict__ cnorm,
        float* __restrict__ lossAcc, unsigned int* __restrict__ doneCnt,
        float* __restrict__ out)
{
    __shared__ __align__(16) unsigned short xs[ROWS * D];   // 32 KB, swizzled 16B segs
    __shared__ unsigned int rowMinU[ROWS];
    __shared__ unsigned long long rowBest[ROWS];
    __shared__ int ccnt[ROWS];
    __shared__ int cand[ROWS][MAXC];
    __shared__ int pairs[MAXP];
    __shared__ int pcnt;
    __shared__ int widx[ROWS];
    __shared__ float wsum[4];
    __shared__ float distSum;

    const int tid = threadIdx.x;
    const int wave = tid >> 6;
    const int lane = tid & 63;
    const int quad = lane >> 4;
    const int col  = lane & 15;
    const int rowBase = blockIdx.x * ROWS;
    const float* xblk = x + (size_t)rowBase * D;

    if (tid < ROWS) { rowMinU[tid] = 0xFFFFFFFFu; rowBest[tid] = ~0ull; ccnt[tid] = 0; }
    if (tid == 0) pcnt = 0;

    // ---- stage x -> bf16 LDS once (seg slot = seg ^ (row & 31)); accumulate sum(x^2) ----
    float xsq = 0.f;
#pragma unroll
    for (int it = 0; it < 16; ++it) {
        int e = tid + it * 256;                 // 4096 float4
        int r = e >> 6;
        int d4 = (e & 63) << 2;
        float4 v = *(const float4*)&xblk[r * D + d4];
        xsq += v.x * v.x + v.y * v.y + v.z * v.z + v.w * v.w;
        int slot = (d4 >> 3) ^ (r & 31);
        *(ushort4*)&xs[r * D + slot * 8 + (d4 & 4)] =
            make_ushort4(f2bf(v.x), f2bf(v.y), f2bf(v.z), f2bf(v.w));
    }
    __syncthreads();

    // ---- coarse bf16 MFMA search: barrier-free K-loop, B direct from L2 ----
    for (int g = 0; g < NG; ++g) {
        floatx4 acc[4][4];
#pragma unroll
        for (int i = 0; i < 4; ++i)
#pragma unroll
            for (int j = 0; j < 4; ++j) acc[i][j] = (floatx4){0.f, 0.f, 0.f, 0.f};

#pragma unroll
        for (int kb = 0; kb < NKB; ++kb) {
            bf16x8 af[4], bfr[4];
#pragma unroll
            for (int i = 0; i < 4; ++i) {
                int r = i * 16 + col;
                int slot = (kb * 4 + quad) ^ (r & 31);
                af[i] = *(const bf16x8*)&xs[r * D + slot * 8];
            }
#pragma unroll
            for (int j = 0; j < 4; ++j) {
                int S = ((g * 8 + kb) * 4 + wave) * 4 + j;
                bfr[j] = *(const bf16x8*)(cbf + (size_t)S * 512 + lane * 8);
            }
#pragma unroll
            for (int j = 0; j < 4; ++j)
#pragma unroll
                for (int i = 0; i < 4; ++i)
                    acc[i][j] = __builtin_amdgcn_mfma_f32_16x16x32_bf16(af[i], bfr[j], acc[i][j], 0, 0, 0);
        }

        // ---- group epilogue: running per-row min, then candidate collect ----
        const int cbase = g * GROUPC + wave * 64;
        float cn[4];
#pragma unroll
        for (int j = 0; j < 4; ++j) cn[j] = cnorm[cbase + j * 16 + col];

#pragma unroll
        for (int i = 0; i < 4; ++i)
#pragma unroll
            for (int reg = 0; reg < 4; ++reg) {
                float v = cn[0] - 2.f * acc[i][0][reg];
#pragma unroll
                for (int j = 1; j < 4; ++j)
                    v = fminf(v, cn[j] - 2.f * acc[i][j][reg]);
#pragma unroll
                for (int off = 1; off < 16; off <<= 1)
                    v = fminf(v, __shfl_xor(v, off, 64));
                if (col == 0)
                    atomicMin(&rowMinU[i * 16 + quad * 4 + reg], fkey(v));
            }
        __syncthreads();   // bound includes this group before collect
#pragma unroll
        for (int i = 0; i < 4; ++i)
#pragma unroll
            for (int reg = 0; reg < 4; ++reg) {
                int row = i * 16 + quad * 4 + reg;
                float lim = unfkey(rowMinU[row]) + MARGIN;
#pragma unroll
                for (int j = 0; j < 4; ++j) {
                    float d2 = cn[j] - 2.f * acc[i][j][reg];
                    if (d2 < lim) {
                        int slot = atomicAdd(&ccnt[row], 1);
                        if (slot < MAXC) cand[row][slot] = cbase + j * 16 + col;
                    }
                }
            }
    }
    __syncthreads();

    // ---- build compact (row,code) pair list ----
    if (tid < ROWS) {
        int m = ccnt[tid]; if (m > MAXC) m = MAXC;
        for (int c = 0; c < m; ++c) {
            int p = atomicAdd(&pcnt, 1);
            pairs[p] = (tid << 10) | cand[tid][c];   // can't exceed MAXP by construction
        }
    }
    __syncthreads();
    const int np = pcnt;

    // ---- exact fp32 rescore: 16 lane-teams of 16, one pair per team-step ----
    const int team = wave * 4 + quad;
    for (int p = team; p < np; p += 16) {
        int pr = pairs[p];
        int row = pr >> 10, code = pr & 1023;
        const float* xr = xblk + row * D + col * 16;
        const float* er = cb + (size_t)code * D + col * 16;
        float s = 0.f;
#pragma unroll
        for (int q = 0; q < 4; ++q) {
            float4 a = *(const float4*)(xr + q * 4);
            float4 b = *(const float4*)(er + q * 4);
            s += a.x * b.x + a.y * b.y + a.z * b.z + a.w * b.w;
        }
#pragma unroll
        for (int off = 1; off < 16; off <<= 1) s += __shfl_xor(s, off, 64);
        if (col == 0) {
            float dist = cnorm[code] - 2.f * s;
            unsigned long long pack = ((unsigned long long)fkey(dist) << 32) | (unsigned int)code;
            atomicMin(&rowBest[row], pack);
        }
    }

    // ---- overflow fallback (~never): exact full scan for rows with ccnt > MAXC ----
    for (int rr = 0; rr < 16; ++rr) {
        const int rl = wave * 16 + rr;
        if (ccnt[rl] > MAXC) {
            float best = 3.4e38f;
            int bi = 0x7fffffff;
            for (int c = lane; c < K; c += 64) {
                float p = 0.f;
                for (int k = 0; k < D; ++k) p += xblk[rl * D + k] * cb[(size_t)c * D + k];
                float dist = cnorm[c] - 2.f * p;
                if (dist < best || (dist == best && c < bi)) { best = dist; bi = c; }
            }
#pragma unroll
            for (int off = 1; off < 64; off <<= 1) {
                float ob = __shfl_xor(best, off, 64);
                int oi = __shfl_xor(bi, off, 64);
                if (ob < best || (ob == best && oi < bi)) { best = ob; bi = oi; }
            }
            if (lane == 0)
                atomicMin(&rowBest[rl], ((unsigned long long)fkey(best) << 32) | (unsigned int)bi);
        }
    }
    __syncthreads();
    if (tid < ROWS) {
        widx[tid] = (int)(rowBest[tid] & 0xffffffffu);
        // exact per-row distance (||e||^2 - 2 x.e) came through the fp32 rescore key
        float dd = unfkey((unsigned int)(rowBest[tid] >> 32));
#pragma unroll
        for (int off = 32; off > 0; off >>= 1) dd += __shfl_down(dd, off, 64);
        if (tid == 0) distSum = dd;
    }
    __syncthreads();

    // ---- gather only (no x re-read; loss = sum(x^2) + sum(dist)) ----
#pragma unroll
    for (int it = 0; it < 16; ++it) {
        int e4 = tid + it * 256;              // ROWS*D/4 = 4096 float4
        int r = e4 >> 6, d4 = (e4 & 63) * 4;
        float4 q = *(const float4*)&cb[(size_t)widx[r] * D + d4];
        *(float4*)&out[(size_t)rowBase * D + r * D + d4] = q;
    }
#pragma unroll
    for (int off = 32; off > 0; off >>= 1) xsq += __shfl_down(xsq, off, 64);
    if (lane == 0) wsum[wave] = xsq;
    __syncthreads();
    if (tid == 0) {
        float tot = wsum[0] + wsum[1] + wsum[2] + wsum[3] + distSum;
        atomicAdd(lossAcc, tot);
        __threadfence();
        if (atomicAdd(doneCnt, 1u) == (unsigned int)(gridDim.x - 1)) {
            float v = atomicAdd(lossAcc, 0.0f);   // device-scope read-back
            out[(size_t)NVEC * D] = 1.25f * v / 16777216.f;  // q_latent + 0.25*e_latent
        }
    }
}

extern "C" void kernel_launch(void* const* d_in, const int* in_sizes, int n_in,
                              void* d_out, int out_size, void* d_ws, size_t ws_size,
                              hipStream_t stream) {
    const float* x  = (const float*)d_in[0];
    const float* cb = (const float*)d_in[1];
    float* out = (float*)d_out;

    float* cnorm = (float*)d_ws;                                  // 4KB
    float* lossAcc = cnorm + K;                                   // @4KB
    unsigned int* doneCnt = (unsigned int*)(lossAcc + 1);         // @4KB+4
    unsigned short* cbf = (unsigned short*)((char*)d_ws + 8192);  // 512KB

    vq_prep<<<K, 64, 0, stream>>>(cb, cnorm, cbf, lossAcc, doneCnt);
    vq_fused<<<NVEC / ROWS, 256, 0, stream>>>(x, cb, cbf, cnorm, lossAcc, doneCnt, out);
}

// Round 3
// 255.803 us; speedup vs baseline: 1.1336x; 1.1336x over previous
//
#include <hip/hip_runtime.h>

#define D 256
#define K 1024
#define NVEC 65536
#define ROWS 64       // rows per block
#define GROUPC 256    // codes per group (per-wave slice = 64)
#define NG (K / GROUPC)
#define NKB (D / 32)  // 8 k-steps of 32
#define MARGIN 0.5f   // ~7 sigma of bf16 coarse-distance error
#define MAXC 12
#define MAXP (ROWS * MAXC)

typedef __attribute__((ext_vector_type(8))) __bf16 bf16x8;
typedef __attribute__((ext_vector_type(4))) float floatx4;

__device__ inline unsigned short f2bf(float f) {  // RNE fp32->bf16
    unsigned int u = __float_as_uint(f);
    unsigned int r = u + 0x7fffu + ((u >> 16) & 1u);
    return (unsigned short)(r >> 16);
}
__device__ inline unsigned int fkey(float f) {    // order-preserving float->uint
    unsigned int b = __float_as_uint(f);
    return (b & 0x80000000u) ? ~b : (b | 0x80000000u);
}
__device__ inline float unfkey(unsigned int k) {
    unsigned int b = (k & 0x80000000u) ? (k & 0x7fffffffu) : ~k;
    return __uint_as_float(b);
}

// ws: cnorm fp32 [0,4KB) | lossAcc @4KB | cbf bf16 (B-fragment order) @8KB (512KB)

// cbf layout: code c -> g=c>>8, w=(c>>6)&3, j=(c>>4)&3, col=c&15 ; k -> kb=k>>5,
// quad=(k>>3)&3, h=k&7.  16B seg index = S*64 + quad*16+col, S=((g*8+kb)*4+w)*4+j.
// In the k-loop, wave w / group g / kb / j reads seg S*64+lane => base + lane*16B.
__global__ void vq_prep(const float* __restrict__ cb, float* __restrict__ cnorm,
                        unsigned short* __restrict__ cbf, float* __restrict__ lossAcc) {
    const int c = blockIdx.x;
    const int l = threadIdx.x;
    float4 v = *(const float4*)&cb[c * D + l * 4];
    float s = v.x * v.x + v.y * v.y + v.z * v.z + v.w * v.w;
#pragma unroll
    for (int off = 32; off > 0; off >>= 1) s += __shfl_down(s, off, 64);
    if (l == 0) cnorm[c] = s;
    const int g = c >> 8, w = (c >> 6) & 3, j = (c >> 4) & 3, col = c & 15;
    const int kb = l >> 3, quad = (l >> 1) & 3, h = (l & 1) * 4;
    const int S = ((g * 8 + kb) * 4 + w) * 4 + j;
    *(ushort4*)(cbf + (size_t)S * 512 + (quad * 16 + col) * 8 + h) =
        make_ushort4(f2bf(v.x), f2bf(v.y), f2bf(v.z), f2bf(v.w));
    if (c == 0 && l == 0) *lossAcc = 0.f;
}

__global__ __launch_bounds__(256, 4) void vq_fused(
        const float* __restrict__ x, const float* __restrict__ cb,
        const unsigned short* __restrict__ cbf, const float* __restrict__ cnorm,
        float* __restrict__ lossAcc, float* __restrict__ out)
{
    __shared__ __align__(16) unsigned short xs[ROWS * D];   // 32 KB, swizzled 16B segs
    __shared__ unsigned int rowMinU[ROWS];
    __shared__ unsigned long long rowBest[ROWS];
    __shared__ int ccnt[ROWS];
    __shared__ int cand[ROWS][MAXC];
    __shared__ int pairs[MAXP];
    __shared__ int pcnt;
    __shared__ int widx[ROWS];
    __shared__ float wsum[4];
    __shared__ float distSum;

    const int tid = threadIdx.x;
    const int wave = tid >> 6;
    const int lane = tid & 63;
    const int quad = lane >> 4;
    const int col  = lane & 15;
    const int rowBase = blockIdx.x * ROWS;
    const float* xblk = x + (size_t)rowBase * D;

    if (tid < ROWS) { rowMinU[tid] = 0xFFFFFFFFu; rowBest[tid] = ~0ull; ccnt[tid] = 0; }
    if (tid == 0) pcnt = 0;

    // ---- stage x -> bf16 LDS once (seg slot = seg ^ (row & 31)); accumulate sum(x^2) ----
    float xsq = 0.f;
#pragma unroll
    for (int it = 0; it < 16; ++it) {
        int e = tid + it * 256;                 // 4096 float4
        int r = e >> 6;
        int d4 = (e & 63) << 2;
        float4 v = *(const float4*)&xblk[r * D + d4];
        xsq += v.x * v.x + v.y * v.y + v.z * v.z + v.w * v.w;
        int slot = (d4 >> 3) ^ (r & 31);
        *(ushort4*)&xs[r * D + slot * 8 + (d4 & 4)] =
            make_ushort4(f2bf(v.x), f2bf(v.y), f2bf(v.z), f2bf(v.w));
    }
    __syncthreads();

    // ---- coarse bf16 MFMA search: barrier-free K-loop, B direct from L2 ----
    for (int g = 0; g < NG; ++g) {
        floatx4 acc[4][4];
#pragma unroll
        for (int i = 0; i < 4; ++i)
#pragma unroll
            for (int j = 0; j < 4; ++j) acc[i][j] = (floatx4){0.f, 0.f, 0.f, 0.f};

#pragma unroll
        for (int kb = 0; kb < NKB; ++kb) {
            bf16x8 af[4], bfr[4];
#pragma unroll
            for (int i = 0; i < 4; ++i) {
                int r = i * 16 + col;
                int slot = (kb * 4 + quad) ^ (r & 31);
                af[i] = *(const bf16x8*)&xs[r * D + slot * 8];
            }
#pragma unroll
            for (int j = 0; j < 4; ++j) {
                int S = ((g * 8 + kb) * 4 + wave) * 4 + j;
                bfr[j] = *(const bf16x8*)(cbf + (size_t)S * 512 + lane * 8);
            }
#pragma unroll
            for (int j = 0; j < 4; ++j)
#pragma unroll
                for (int i = 0; i < 4; ++i)
                    acc[i][j] = __builtin_amdgcn_mfma_f32_16x16x32_bf16(af[i], bfr[j], acc[i][j], 0, 0, 0);
        }

        // ---- group epilogue: running per-row min, then candidate collect ----
        const int cbase = g * GROUPC + wave * 64;
        float cn[4];
#pragma unroll
        for (int j = 0; j < 4; ++j) cn[j] = cnorm[cbase + j * 16 + col];

#pragma unroll
        for (int i = 0; i < 4; ++i)
#pragma unroll
            for (int reg = 0; reg < 4; ++reg) {
                float v = cn[0] - 2.f * acc[i][0][reg];
#pragma unroll
                for (int j = 1; j < 4; ++j)
                    v = fminf(v, cn[j] - 2.f * acc[i][j][reg]);
#pragma unroll
                for (int off = 1; off < 16; off <<= 1)
                    v = fminf(v, __shfl_xor(v, off, 64));
                if (col == 0)
                    atomicMin(&rowMinU[i * 16 + quad * 4 + reg], fkey(v));
            }
        __syncthreads();   // bound includes this group before collect
#pragma unroll
        for (int i = 0; i < 4; ++i)
#pragma unroll
            for (int reg = 0; reg < 4; ++reg) {
                int row = i * 16 + quad * 4 + reg;
                float lim = unfkey(rowMinU[row]) + MARGIN;
#pragma unroll
                for (int j = 0; j < 4; ++j) {
                    float d2 = cn[j] - 2.f * acc[i][j][reg];
                    if (d2 < lim) {
                        int slot = atomicAdd(&ccnt[row], 1);
                        if (slot < MAXC) cand[row][slot] = cbase + j * 16 + col;
                    }
                }
            }
    }

    // ---- coalesced x prefetch burst: re-warm L2 for the exact rescore ----
    // (rescore reads every row's full fp32 x; scattered 16B/lane misses at ~900cy
    //  would serialize behind the per-pair shuffle-reduce. Issue the whole 64KB
    //  as wave-wide float4 loads here; latency overlaps pair-list building.)
    float pf = 0.f;
#pragma unroll
    for (int it = 0; it < 16; ++it) {
        int e = tid + it * 256;
        int r = e >> 6;
        int d4 = (e & 63) << 2;
        float4 v = *(const float4*)&xblk[r * D + d4];
        pf += v.x;
    }
    __syncthreads();

    // ---- build compact (row,code) pair list ----
    if (tid < ROWS) {
        int m = ccnt[tid]; if (m > MAXC) m = MAXC;
        for (int c = 0; c < m; ++c) {
            int p = atomicAdd(&pcnt, 1);
            pairs[p] = (tid << 10) | cand[tid][c];   // can't exceed MAXP by construction
        }
    }
    __syncthreads();
    const int np = pcnt;
    asm volatile("" : : "v"(pf));   // keep prefetch live (no DCE)

    // ---- exact fp32 rescore: 16 lane-teams of 16, one pair per team-step ----
    const int team = wave * 4 + quad;
    for (int p = team; p < np; p += 16) {
        int pr = pairs[p];
        int row = pr >> 10, code = pr & 1023;
        const float* xr = xblk + row * D + col * 16;
        const float* er = cb + (size_t)code * D + col * 16;
        float s = 0.f;
#pragma unroll
        for (int q = 0; q < 4; ++q) {
            float4 a = *(const float4*)(xr + q * 4);
            float4 b = *(const float4*)(er + q * 4);
            s += a.x * b.x + a.y * b.y + a.z * b.z + a.w * b.w;
        }
#pragma unroll
        for (int off = 1; off < 16; off <<= 1) s += __shfl_xor(s, off, 64);
        if (col == 0) {
            float dist = cnorm[code] - 2.f * s;
            unsigned long long pack = ((unsigned long long)fkey(dist) << 32) | (unsigned int)code;
            atomicMin(&rowBest[row], pack);
        }
    }

    // ---- overflow fallback (~never): exact full scan for rows with ccnt > MAXC ----
    for (int rr = 0; rr < 16; ++rr) {
        const int rl = wave * 16 + rr;
        if (ccnt[rl] > MAXC) {
            float best = 3.4e38f;
            int bi = 0x7fffffff;
            for (int c = lane; c < K; c += 64) {
                float p = 0.f;
                for (int k = 0; k < D; ++k) p += xblk[rl * D + k] * cb[(size_t)c * D + k];
                float dist = cnorm[c] - 2.f * p;
                if (dist < best || (dist == best && c < bi)) { best = dist; bi = c; }
            }
#pragma unroll
            for (int off = 1; off < 64; off <<= 1) {
                float ob = __shfl_xor(best, off, 64);
                int oi = __shfl_xor(bi, off, 64);
                if (ob < best || (ob == best && oi < bi)) { best = ob; bi = oi; }
            }
            if (lane == 0)
                atomicMin(&rowBest[rl], ((unsigned long long)fkey(best) << 32) | (unsigned int)bi);
        }
    }
    __syncthreads();
    if (tid < ROWS) {
        widx[tid] = (int)(rowBest[tid] & 0xffffffffu);
        // exact per-row distance (||e||^2 - 2 x.e) came through the fp32 rescore key
        float dd = unfkey((unsigned int)(rowBest[tid] >> 32));
#pragma unroll
        for (int off = 32; off > 0; off >>= 1) dd += __shfl_down(dd, off, 64);
        if (tid == 0) distSum = dd;
    }
    __syncthreads();

    // ---- gather only (no x re-read; loss = sum(x^2) + sum(dist)) ----
    // out is never re-read: non-temporal stores keep the 64MB write stream
    // from evicting x/cb/cbf in L2 for concurrently-running blocks.
#pragma unroll
    for (int it = 0; it < 16; ++it) {
        int e4 = tid + it * 256;              // ROWS*D/4 = 4096 float4
        int r = e4 >> 6, d4 = (e4 & 63) * 4;
        floatx4 q = *(const floatx4*)&cb[(size_t)widx[r] * D + d4];
        __builtin_nontemporal_store(q, (floatx4*)&out[(size_t)rowBase * D + r * D + d4]);
    }
#pragma unroll
    for (int off = 32; off > 0; off >>= 1) xsq += __shfl_down(xsq, off, 64);
    if (lane == 0) wsum[wave] = xsq;
    __syncthreads();
    if (tid == 0) atomicAdd(lossAcc, wsum[0] + wsum[1] + wsum[2] + wsum[3] + distSum);
}

__global__ void vq_final_kernel(const float* __restrict__ lossAcc, float* __restrict__ outLoss) {
    *outLoss = 1.25f * (*lossAcc) / 16777216.f;  // q_latent + 0.25*e_latent
}

extern "C" void kernel_launch(void* const* d_in, const int* in_sizes, int n_in,
                              void* d_out, int out_size, void* d_ws, size_t ws_size,
                              hipStream_t stream) {
    const float* x  = (const float*)d_in[0];
    const float* cb = (const float*)d_in[1];
    float* out = (float*)d_out;

    float* cnorm = (float*)d_ws;                                  // 4KB
    float* lossAcc = cnorm + K;                                   // @4KB
    unsigned short* cbf = (unsigned short*)((char*)d_ws + 8192);  // 512KB

    vq_prep<<<K, 64, 0, stream>>>(cb, cnorm, cbf, lossAcc);
    vq_fused<<<NVEC / ROWS, 256, 0, stream>>>(x, cb, cbf, cnorm, lossAcc, out);
    vq_final_kernel<<<1, 1, 0, stream>>>(lossAcc, out + (size_t)NVEC * D);
}

// Round 4
// 253.507 us; speedup vs baseline: 1.1439x; 1.0091x over previous
//
#include <hip/hip_runtime.h>

#define D 256
#define K 1024
#define NVEC 65536
#define ROWS 64       // rows per block
#define GROUPC 256    // codes per group (per-wave slice = 64)
#define NG (K / GROUPC)
#define NKB (D / 32)  // 8 k-steps of 32
#define MARGIN 0.5f   // ~7 sigma of bf16 coarse-distance error
#define MAXC 12
#define MAXP (ROWS * MAXC)

typedef __attribute__((ext_vector_type(8))) __bf16 bf16x8;
typedef __attribute__((ext_vector_type(4))) float floatx4;

__device__ inline unsigned short f2bf(float f) {  // RNE fp32->bf16
    unsigned int u = __float_as_uint(f);
    unsigned int r = u + 0x7fffu + ((u >> 16) & 1u);
    return (unsigned short)(r >> 16);
}
__device__ inline unsigned int fkey(float f) {    // order-preserving float->uint
    unsigned int b = __float_as_uint(f);
    return (b & 0x80000000u) ? ~b : (b | 0x80000000u);
}
__device__ inline float unfkey(unsigned int k) {
    unsigned int b = (k & 0x80000000u) ? (k & 0x7fffffffu) : ~k;
    return __uint_as_float(b);
}

// ws: cnorm fp32 [0,4KB) | lossAcc @4KB | cbf bf16 (B-fragment order) @8KB (512KB)

// cbf layout: code c -> g=c>>8, w=(c>>6)&3, j=(c>>4)&3, col=c&15 ; k -> kb=k>>5,
// quad=(k>>3)&3, h=k&7.  16B seg index = S*64 + quad*16+col, S=((g*8+kb)*4+w)*4+j.
// In the k-loop, wave w / group g / kb / j reads seg S*64+lane => base + lane*16B.
__global__ void vq_prep(const float* __restrict__ cb, float* __restrict__ cnorm,
                        unsigned short* __restrict__ cbf, float* __restrict__ lossAcc) {
    const int c = blockIdx.x;
    const int l = threadIdx.x;
    float4 v = *(const float4*)&cb[c * D + l * 4];
    float s = v.x * v.x + v.y * v.y + v.z * v.z + v.w * v.w;
#pragma unroll
    for (int off = 32; off > 0; off >>= 1) s += __shfl_down(s, off, 64);
    if (l == 0) cnorm[c] = s;
    const int g = c >> 8, w = (c >> 6) & 3, j = (c >> 4) & 3, col = c & 15;
    const int kb = l >> 3, quad = (l >> 1) & 3, h = (l & 1) * 4;
    const int S = ((g * 8 + kb) * 4 + w) * 4 + j;
    *(ushort4*)(cbf + (size_t)S * 512 + (quad * 16 + col) * 8 + h) =
        make_ushort4(f2bf(v.x), f2bf(v.y), f2bf(v.z), f2bf(v.w));
    if (c == 0 && l == 0) *lossAcc = 0.f;
}

__global__ __launch_bounds__(256, 4) void vq_fused(
        const float* __restrict__ x, const float* __restrict__ cb,
        const unsigned short* __restrict__ cbf, const float* __restrict__ cnorm,
        float* __restrict__ lossAcc, float* __restrict__ out)
{
    __shared__ __align__(16) unsigned short xs[ROWS * D];   // 32 KB, swizzled 16B segs
    __shared__ unsigned int rowMinU[ROWS];
    __shared__ unsigned long long rowBest[ROWS];
    __shared__ int ccnt[ROWS];
    __shared__ int cand[ROWS][MAXC];
    __shared__ int pairs[MAXP];
    __shared__ int pcnt;
    __shared__ int widx[ROWS];
    __shared__ float wsum[4];
    __shared__ float distSum;

    const int tid = threadIdx.x;
    const int wave = tid >> 6;
    const int lane = tid & 63;
    const int quad = lane >> 4;
    const int col  = lane & 15;
    const int rowBase = blockIdx.x * ROWS;
    const float* xblk = x + (size_t)rowBase * D;

    if (tid < ROWS) { rowMinU[tid] = 0xFFFFFFFFu; rowBest[tid] = ~0ull; ccnt[tid] = 0; }
    if (tid == 0) pcnt = 0;

    // ---- stage x -> bf16 LDS once (seg slot = seg ^ (row & 31)); accumulate sum(x^2) ----
    float xsq = 0.f;
#pragma unroll
    for (int it = 0; it < 16; ++it) {
        int e = tid + it * 256;                 // 4096 float4
        int r = e >> 6;
        int d4 = (e & 63) << 2;
        float4 v = *(const float4*)&xblk[r * D + d4];
        xsq += v.x * v.x + v.y * v.y + v.z * v.z + v.w * v.w;
        int slot = (d4 >> 3) ^ (r & 31);
        *(ushort4*)&xs[r * D + slot * 8 + (d4 & 4)] =
            make_ushort4(f2bf(v.x), f2bf(v.y), f2bf(v.z), f2bf(v.w));
    }
    __syncthreads();

    // ---- coarse bf16 MFMA search: barrier-free K-loop, B direct from L2 ----
    for (int g = 0; g < NG; ++g) {
        floatx4 acc[4][4];
#pragma unroll
        for (int i = 0; i < 4; ++i)
#pragma unroll
            for (int j = 0; j < 4; ++j) acc[i][j] = (floatx4){0.f, 0.f, 0.f, 0.f};

#pragma unroll
        for (int kb = 0; kb < NKB; ++kb) {
            bf16x8 af[4], bfr[4];
#pragma unroll
            for (int i = 0; i < 4; ++i) {
                int r = i * 16 + col;
                int slot = (kb * 4 + quad) ^ (r & 31);
                af[i] = *(const bf16x8*)&xs[r * D + slot * 8];
            }
#pragma unroll
            for (int j = 0; j < 4; ++j) {
                int S = ((g * 8 + kb) * 4 + wave) * 4 + j;
                bfr[j] = *(const bf16x8*)(cbf + (size_t)S * 512 + lane * 8);
            }
#pragma unroll
            for (int j = 0; j < 4; ++j)
#pragma unroll
                for (int i = 0; i < 4; ++i)
                    acc[i][j] = __builtin_amdgcn_mfma_f32_16x16x32_bf16(af[i], bfr[j], acc[i][j], 0, 0, 0);
        }

        // ---- group epilogue: running per-row min, then candidate collect ----
        const int cbase = g * GROUPC + wave * 64;
        float cn[4];
#pragma unroll
        for (int j = 0; j < 4; ++j) cn[j] = cnorm[cbase + j * 16 + col];

#pragma unroll
        for (int i = 0; i < 4; ++i)
#pragma unroll
            for (int reg = 0; reg < 4; ++reg) {
                float v = cn[0] - 2.f * acc[i][0][reg];
#pragma unroll
                for (int j = 1; j < 4; ++j)
                    v = fminf(v, cn[j] - 2.f * acc[i][j][reg]);
#pragma unroll
                for (int off = 1; off < 16; off <<= 1)
                    v = fminf(v, __shfl_xor(v, off, 64));
                if (col == 0)
                    atomicMin(&rowMinU[i * 16 + quad * 4 + reg], fkey(v));
            }
        __syncthreads();   // bound includes this group before collect
#pragma unroll
        for (int i = 0; i < 4; ++i)
#pragma unroll
            for (int reg = 0; reg < 4; ++reg) {
                int row = i * 16 + quad * 4 + reg;
                float lim = unfkey(rowMinU[row]) + MARGIN;
#pragma unroll
                for (int j = 0; j < 4; ++j) {
                    float d2 = cn[j] - 2.f * acc[i][j][reg];
                    if (d2 < lim) {
                        int slot = atomicAdd(&ccnt[row], 1);
                        if (slot < MAXC) cand[row][slot] = cbase + j * 16 + col;
                    }
                }
            }
    }
    __syncthreads();

    // ---- build compact (row,code) pair list ----
    if (tid < ROWS) {
        int m = ccnt[tid]; if (m > MAXC) m = MAXC;
        for (int c = 0; c < m; ++c) {
            int p = atomicAdd(&pcnt, 1);
            pairs[p] = (tid << 10) | cand[tid][c];   // can't exceed MAXP by construction
        }
    }
    __syncthreads();
    const int np = pcnt;

    // ---- exact fp32 rescore: 16 lane-teams of 16, one pair per team-step ----
    const int team = wave * 4 + quad;
    for (int p = team; p < np; p += 16) {
        int pr = pairs[p];
        int row = pr >> 10, code = pr & 1023;
        const float* xr = xblk + row * D + col * 16;
        const float* er = cb + (size_t)code * D + col * 16;
        float s = 0.f;
#pragma unroll
        for (int q = 0; q < 4; ++q) {
            float4 a = *(const float4*)(xr + q * 4);
            float4 b = *(const float4*)(er + q * 4);
            s += a.x * b.x + a.y * b.y + a.z * b.z + a.w * b.w;
        }
#pragma unroll
        for (int off = 1; off < 16; off <<= 1) s += __shfl_xor(s, off, 64);
        if (col == 0) {
            float dist = cnorm[code] - 2.f * s;
            unsigned long long pack = ((unsigned long long)fkey(dist) << 32) | (unsigned int)code;
            atomicMin(&rowBest[row], pack);
        }
    }

    // ---- overflow fallback (~never): exact full scan for rows with ccnt > MAXC ----
    for (int rr = 0; rr < 16; ++rr) {
        const int rl = wave * 16 + rr;
        if (ccnt[rl] > MAXC) {
            float best = 3.4e38f;
            int bi = 0x7fffffff;
            for (int c = lane; c < K; c += 64) {
                float p = 0.f;
                for (int k = 0; k < D; ++k) p += xblk[rl * D + k] * cb[(size_t)c * D + k];
                float dist = cnorm[c] - 2.f * p;
                if (dist < best || (dist == best && c < bi)) { best = dist; bi = c; }
            }
#pragma unroll
            for (int off = 1; off < 64; off <<= 1) {
                float ob = __shfl_xor(best, off, 64);
                int oi = __shfl_xor(bi, off, 64);
                if (ob < best || (ob == best && oi < bi)) { best = ob; bi = oi; }
            }
            if (lane == 0)
                atomicMin(&rowBest[rl], ((unsigned long long)fkey(best) << 32) | (unsigned int)bi);
        }
    }
    __syncthreads();
    if (tid < ROWS) {
        widx[tid] = (int)(rowBest[tid] & 0xffffffffu);
        // exact per-row distance (||e||^2 - 2 x.e) came through the fp32 rescore key
        float dd = unfkey((unsigned int)(rowBest[tid] >> 32));
#pragma unroll
        for (int off = 32; off > 0; off >>= 1) dd += __shfl_down(dd, off, 64);
        if (tid == 0) distSum = dd;
    }
    __syncthreads();

    // ---- gather only (no x re-read; loss = sum(x^2) + sum(dist)); normal stores ----
#pragma unroll
    for (int it = 0; it < 16; ++it) {
        int e4 = tid + it * 256;              // ROWS*D/4 = 4096 float4
        int r = e4 >> 6, d4 = (e4 & 63) * 4;
        float4 q = *(const float4*)&cb[(size_t)widx[r] * D + d4];
        *(float4*)&out[(size_t)rowBase * D + r * D + d4] = q;
    }
#pragma unroll
    for (int off = 32; off > 0; off >>= 1) xsq += __shfl_down(xsq, off, 64);
    if (lane == 0) wsum[wave] = xsq;
    __syncthreads();
    if (tid == 0) atomicAdd(lossAcc, wsum[0] + wsum[1] + wsum[2] + wsum[3] + distSum);
}

__global__ void vq_final_kernel(const float* __restrict__ lossAcc, float* __restrict__ outLoss) {
    *outLoss = 1.25f * (*lossAcc) / 16777216.f;  // q_latent + 0.25*e_latent
}

extern "C" void kernel_launch(void* const* d_in, const int* in_sizes, int n_in,
                              void* d_out, int out_size, void* d_ws, size_t ws_size,
                              hipStream_t stream) {
    const float* x  = (const float*)d_in[0];
    const float* cb = (const float*)d_in[1];
    float* out = (float*)d_out;

    float* cnorm = (float*)d_ws;                                  // 4KB
    float* lossAcc = cnorm + K;                                   // @4KB
    unsigned short* cbf = (unsigned short*)((char*)d_ws + 8192);  // 512KB

    vq_prep<<<K, 64, 0, stream>>>(cb, cnorm, cbf, lossAcc);
    vq_fused<<<NVEC / ROWS, 256, 0, stream>>>(x, cb, cbf, cnorm, lossAcc, out);
    vq_final_kernel<<<1, 1, 0, stream>>>(lossAcc, out + (size_t)NVEC * D);
}

// Round 5
// 231.375 us; speedup vs baseline: 1.2533x; 1.0957x over previous
//
#include <hip/hip_runtime.h>

#define D 256
#define K 1024
#define NVEC 65536
#define ROWS 32       // rows per block (halved: more blocks -> latency hiding via TLP)
#define GROUPC 256    // codes per group (per-wave slice = 64)
#define NG (K / GROUPC)
#define NKB (D / 32)  // 8 k-steps of 32
#define MARGIN 0.5f   // ~7 sigma of bf16 coarse-distance error
#define MAXC 12
#define MAXP (ROWS * MAXC)

typedef __attribute__((ext_vector_type(8))) __bf16 bf16x8;
typedef __attribute__((ext_vector_type(4))) float floatx4;

__device__ inline unsigned short f2bf(float f) {  // RNE fp32->bf16
    unsigned int u = __float_as_uint(f);
    unsigned int r = u + 0x7fffu + ((u >> 16) & 1u);
    return (unsigned short)(r >> 16);
}
__device__ inline unsigned int fkey(float f) {    // order-preserving float->uint
    unsigned int b = __float_as_uint(f);
    return (b & 0x80000000u) ? ~b : (b | 0x80000000u);
}
__device__ inline float unfkey(unsigned int k) {
    unsigned int b = (k & 0x80000000u) ? (k & 0x7fffffffu) : ~k;
    return __uint_as_float(b);
}

// ws: cnorm fp32 [0,4KB) | lossAcc @4KB | cbf bf16 (B-fragment order) @8KB (512KB)

// cbf layout: code c -> g=c>>8, w=(c>>6)&3, j=(c>>4)&3, col=c&15 ; k -> kb=k>>5,
// quad=(k>>3)&3, h=k&7.  16B seg index = S*64 + quad*16+col, S=((g*8+kb)*4+w)*4+j.
// In the k-loop, wave w / group g / kb / j reads seg S*64+lane => base + lane*16B.
__global__ void vq_prep(const float* __restrict__ cb, float* __restrict__ cnorm,
                        unsigned short* __restrict__ cbf, float* __restrict__ lossAcc) {
    const int c = blockIdx.x;
    const int l = threadIdx.x;
    float4 v = *(const float4*)&cb[c * D + l * 4];
    float s = v.x * v.x + v.y * v.y + v.z * v.z + v.w * v.w;
#pragma unroll
    for (int off = 32; off > 0; off >>= 1) s += __shfl_down(s, off, 64);
    if (l == 0) cnorm[c] = s;
    const int g = c >> 8, w = (c >> 6) & 3, j = (c >> 4) & 3, col = c & 15;
    const int kb = l >> 3, quad = (l >> 1) & 3, h = (l & 1) * 4;
    const int S = ((g * 8 + kb) * 4 + w) * 4 + j;
    *(ushort4*)(cbf + (size_t)S * 512 + (quad * 16 + col) * 8 + h) =
        make_ushort4(f2bf(v.x), f2bf(v.y), f2bf(v.z), f2bf(v.w));
    if (c == 0 && l == 0) *lossAcc = 0.f;
}

__global__ __launch_bounds__(256, 5) void vq_fused(
        const float* __restrict__ x, const float* __restrict__ cb,
        const unsigned short* __restrict__ cbf, const float* __restrict__ cnorm,
        float* __restrict__ lossAcc, float* __restrict__ out)
{
    __shared__ __align__(16) unsigned short xs[ROWS * D];   // 16 KB, swizzled 16B segs
    __shared__ unsigned int rowMinU[ROWS];
    __shared__ unsigned long long rowBest[ROWS];
    __shared__ int ccnt[ROWS];
    __shared__ int cand[ROWS][MAXC];
    __shared__ int pairs[MAXP];
    __shared__ int pcnt;
    __shared__ int widx[ROWS];
    __shared__ float wsum[4];

    const int tid = threadIdx.x;
    const int wave = tid >> 6;
    const int lane = tid & 63;
    const int quad = lane >> 4;
    const int col  = lane & 15;
    const int rowBase = blockIdx.x * ROWS;
    const float* xblk = x + (size_t)rowBase * D;

    if (tid < ROWS) { rowMinU[tid] = 0xFFFFFFFFu; rowBest[tid] = ~0ull; ccnt[tid] = 0; }
    if (tid == 0) pcnt = 0;

    // ---- stage x -> bf16 LDS once (seg slot = seg ^ (row & 31)) ----
#pragma unroll
    for (int it = 0; it < ROWS * D / 4 / 256; ++it) {   // 8 iters: 2048 float4
        int e = tid + it * 256;
        int r = e >> 6;
        int d4 = (e & 63) << 2;
        float4 v = *(const float4*)&xblk[r * D + d4];
        int slot = (d4 >> 3) ^ (r & 31);
        *(ushort4*)&xs[r * D + slot * 8 + (d4 & 4)] =
            make_ushort4(f2bf(v.x), f2bf(v.y), f2bf(v.z), f2bf(v.w));
    }
    __syncthreads();

    // ---- coarse bf16 MFMA search: barrier-free K-loop, B direct from L2 ----
    for (int g = 0; g < NG; ++g) {
        floatx4 acc[2][4];
#pragma unroll
        for (int i = 0; i < 2; ++i)
#pragma unroll
            for (int j = 0; j < 4; ++j) acc[i][j] = (floatx4){0.f, 0.f, 0.f, 0.f};

#pragma unroll
        for (int kb = 0; kb < NKB; ++kb) {
            bf16x8 af[2], bfr[4];
#pragma unroll
            for (int i = 0; i < 2; ++i) {
                int r = i * 16 + col;
                int slot = (kb * 4 + quad) ^ (r & 31);
                af[i] = *(const bf16x8*)&xs[r * D + slot * 8];
            }
#pragma unroll
            for (int j = 0; j < 4; ++j) {
                int S = ((g * 8 + kb) * 4 + wave) * 4 + j;
                bfr[j] = *(const bf16x8*)(cbf + (size_t)S * 512 + lane * 8);
            }
#pragma unroll
            for (int j = 0; j < 4; ++j)
#pragma unroll
                for (int i = 0; i < 2; ++i)
                    acc[i][j] = __builtin_amdgcn_mfma_f32_16x16x32_bf16(af[i], bfr[j], acc[i][j], 0, 0, 0);
        }

        // ---- group epilogue: running per-row min, then candidate collect ----
        const int cbase = g * GROUPC + wave * 64;
        float cn[4];
#pragma unroll
        for (int j = 0; j < 4; ++j) cn[j] = cnorm[cbase + j * 16 + col];

#pragma unroll
        for (int i = 0; i < 2; ++i)
#pragma unroll
            for (int reg = 0; reg < 4; ++reg) {
                float v = cn[0] - 2.f * acc[i][0][reg];
#pragma unroll
                for (int j = 1; j < 4; ++j)
                    v = fminf(v, cn[j] - 2.f * acc[i][j][reg]);
#pragma unroll
                for (int off = 1; off < 16; off <<= 1)
                    v = fminf(v, __shfl_xor(v, off, 64));
                if (col == 0)
                    atomicMin(&rowMinU[i * 16 + quad * 4 + reg], fkey(v));
            }
        __syncthreads();   // bound includes this group before collect
#pragma unroll
        for (int i = 0; i < 2; ++i)
#pragma unroll
            for (int reg = 0; reg < 4; ++reg) {
                int row = i * 16 + quad * 4 + reg;
                float lim = unfkey(rowMinU[row]) + MARGIN;
#pragma unroll
                for (int j = 0; j < 4; ++j) {
                    float d2 = cn[j] - 2.f * acc[i][j][reg];
                    if (d2 < lim) {
                        int slot = atomicAdd(&ccnt[row], 1);
                        if (slot < MAXC) cand[row][slot] = cbase + j * 16 + col;
                    }
                }
            }
    }
    __syncthreads();

    // ---- build compact (row,code) pair list ----
    if (tid < ROWS) {
        int m = ccnt[tid]; if (m > MAXC) m = MAXC;
        for (int c = 0; c < m; ++c) {
            int p = atomicAdd(&pcnt, 1);
            pairs[p] = (tid << 10) | cand[tid][c];   // can't exceed MAXP by construction
        }
    }
    __syncthreads();
    const int np = pcnt;

    // ---- exact fp32 rescore: 16 lane-teams of 16, one pair per team-step ----
    const int team = wave * 4 + quad;
    for (int p = team; p < np; p += 16) {
        int pr = pairs[p];
        int row = pr >> 10, code = pr & 1023;
        const float* xr = xblk + row * D + col * 16;
        const float* er = cb + (size_t)code * D + col * 16;
        float s = 0.f;
#pragma unroll
        for (int q = 0; q < 4; ++q) {
            float4 a = *(const float4*)(xr + q * 4);
            float4 b = *(const float4*)(er + q * 4);
            s += a.x * b.x + a.y * b.y + a.z * b.z + a.w * b.w;
        }
#pragma unroll
        for (int off = 1; off < 16; off <<= 1) s += __shfl_xor(s, off, 64);
        if (col == 0) {
            float dist = cnorm[code] - 2.f * s;
            unsigned long long pack = ((unsigned long long)fkey(dist) << 32) | (unsigned int)code;
            atomicMin(&rowBest[row], pack);
        }
    }

    // ---- overflow fallback (~never): exact full scan for rows with ccnt > MAXC ----
    for (int rr = 0; rr < ROWS / 4; ++rr) {
        const int rl = wave * (ROWS / 4) + rr;
        if (ccnt[rl] > MAXC) {
            float best = 3.4e38f;
            int bi = 0x7fffffff;
            for (int c = lane; c < K; c += 64) {
                float p = 0.f;
                for (int k = 0; k < D; ++k) p += xblk[rl * D + k] * cb[(size_t)c * D + k];
                float dist = cnorm[c] - 2.f * p;
                if (dist < best || (dist == best && c < bi)) { best = dist; bi = c; }
            }
#pragma unroll
            for (int off = 1; off < 64; off <<= 1) {
                float ob = __shfl_xor(best, off, 64);
                int oi = __shfl_xor(bi, off, 64);
                if (ob < best || (ob == best && oi < bi)) { best = ob; bi = oi; }
            }
            if (lane == 0)
                atomicMin(&rowBest[rl], ((unsigned long long)fkey(best) << 32) | (unsigned int)bi);
        }
    }
    __syncthreads();
    if (tid < ROWS) widx[tid] = (int)(rowBest[tid] & 0xffffffffu);
    __syncthreads();

    // ---- gather + loss (round-0 structure: x re-read here, loss from q - x) ----
    float part = 0.f;
#pragma unroll
    for (int it = 0; it < ROWS * D / 4 / 256; ++it) {   // 8 iters
        int e4 = tid + it * 256;
        int r = e4 >> 6, d4 = (e4 & 63) * 4;
        float4 q = *(const float4*)&cb[(size_t)widx[r] * D + d4];
        float4 xv = *(const float4*)&xblk[r * D + d4];
        *(float4*)&out[(size_t)rowBase * D + r * D + d4] = q;
        float a = q.x - xv.x, b = q.y - xv.y, c2 = q.z - xv.z, d2 = q.w - xv.w;
        part += a * a + b * b + c2 * c2 + d2 * d2;
    }
#pragma unroll
    for (int off = 32; off > 0; off >>= 1) part += __shfl_down(part, off, 64);
    if (lane == 0) wsum[wave] = part;
    __syncthreads();
    if (tid == 0) atomicAdd(lossAcc, wsum[0] + wsum[1] + wsum[2] + wsum[3]);
}

__global__ void vq_final_kernel(const float* __restrict__ lossAcc, float* __restrict__ outLoss) {
    *outLoss = 1.25f * (*lossAcc) / 16777216.f;  // q_latent + 0.25*e_latent
}

extern "C" void kernel_launch(void* const* d_in, const int* in_sizes, int n_in,
                              void* d_out, int out_size, void* d_ws, size_t ws_size,
                              hipStream_t stream) {
    const float* x  = (const float*)d_in[0];
    const float* cb = (const float*)d_in[1];
    float* out = (float*)d_out;

    float* cnorm = (float*)d_ws;                                  // 4KB
    float* lossAcc = cnorm + K;                                   // @4KB
    unsigned short* cbf = (unsigned short*)((char*)d_ws + 8192);  // 512KB

    vq_prep<<<K, 64, 0, stream>>>(cb, cnorm, cbf, lossAcc);
    vq_fused<<<NVEC / ROWS, 256, 0, stream>>>(x, cb, cbf, cnorm, lossAcc, out);
    vq_final_kernel<<<1, 1, 0, stream>>>(lossAcc, out + (size_t)NVEC * D);
}

// Round 6
// 211.735 us; speedup vs baseline: 1.3695x; 1.0928x over previous
//
#include <hip/hip_runtime.h>

#define D 256
#define K 1024
#define NVEC 65536
#define ROWS 32       // rows per block
#define GROUPC 256    // codes per group (per-wave slice = 64)
#define NG (K / GROUPC)
#define NKB (D / 32)  // 8 k-steps of 32
#define MARGIN 0.5f   // ~7 sigma of bf16 coarse-distance error
#define MAXC 12
#define MAXP (ROWS * MAXC)

typedef __attribute__((ext_vector_type(8))) __bf16 bf16x8;
typedef __attribute__((ext_vector_type(4))) float floatx4;

__device__ inline unsigned short f2bf(float f) {  // RNE fp32->bf16
    unsigned int u = __float_as_uint(f);
    unsigned int r = u + 0x7fffu + ((u >> 16) & 1u);
    return (unsigned short)(r >> 16);
}
__device__ inline unsigned int fkey(float f) {    // order-preserving float->uint
    unsigned int b = __float_as_uint(f);
    return (b & 0x80000000u) ? ~b : (b | 0x80000000u);
}
__device__ inline float unfkey(unsigned int k) {
    unsigned int b = (k & 0x80000000u) ? (k & 0x7fffffffu) : ~k;
    return __uint_as_float(b);
}
__device__ inline bf16x8 pack8(float4 a, float4 b) {  // 8 fp32 -> bf16x8 (RNE)
    union { bf16x8 v; unsigned short u[8]; } t;
    t.u[0] = f2bf(a.x); t.u[1] = f2bf(a.y); t.u[2] = f2bf(a.z); t.u[3] = f2bf(a.w);
    t.u[4] = f2bf(b.x); t.u[5] = f2bf(b.y); t.u[6] = f2bf(b.z); t.u[7] = f2bf(b.w);
    return t.v;
}

// fp32 x LDS swizzle: row r has 64 segs of 16B (4 floats); seg s stored at
// slot = (s & 32) | ((s & 31) ^ (r & 31)).  Bijective per row; af/rescore/gather
// read patterns all land ~uniform across banks (mirrors the proven bf16 scheme).
#define XSLOT(r, s) (((s) & 32) | (((s) & 31) ^ ((r) & 31)))

// ws: cnorm fp32 [0,4KB) | lossAcc @4KB | cbf bf16 (B-fragment order) @8KB (512KB)

// cbf layout: code c -> g=c>>8, w=(c>>6)&3, j=(c>>4)&3, col=c&15 ; k -> kb=k>>5,
// quad=(k>>3)&3, h=k&7.  16B seg index = S*64 + quad*16+col, S=((g*8+kb)*4+w)*4+j.
// In the k-loop, wave w / group g / kb / j reads seg S*64+lane => base + lane*16B.
__global__ void vq_prep(const float* __restrict__ cb, float* __restrict__ cnorm,
                        unsigned short* __restrict__ cbf, float* __restrict__ lossAcc) {
    const int c = blockIdx.x;
    const int l = threadIdx.x;
    float4 v = *(const float4*)&cb[c * D + l * 4];
    float s = v.x * v.x + v.y * v.y + v.z * v.z + v.w * v.w;
#pragma unroll
    for (int off = 32; off > 0; off >>= 1) s += __shfl_down(s, off, 64);
    if (l == 0) cnorm[c] = s;
    const int g = c >> 8, w = (c >> 6) & 3, j = (c >> 4) & 3, col = c & 15;
    const int kb = l >> 3, quad = (l >> 1) & 3, h = (l & 1) * 4;
    const int S = ((g * 8 + kb) * 4 + w) * 4 + j;
    *(ushort4*)(cbf + (size_t)S * 512 + (quad * 16 + col) * 8 + h) =
        make_ushort4(f2bf(v.x), f2bf(v.y), f2bf(v.z), f2bf(v.w));
    if (c == 0 && l == 0) *lossAcc = 0.f;
}

__global__ __launch_bounds__(256, 4) void vq_fused(
        const float* __restrict__ x, const float* __restrict__ cb,
        const unsigned short* __restrict__ cbf, const float* __restrict__ cnorm,
        float* __restrict__ lossAcc, float* __restrict__ out)
{
    __shared__ __align__(16) float xs[ROWS * D];   // 32 KB fp32, swizzled 16B segs
    __shared__ unsigned int rowMinU[ROWS];
    __shared__ unsigned long long rowBest[ROWS];
    __shared__ int ccnt[ROWS];
    __shared__ int cand[ROWS][MAXC];
    __shared__ int pairs[MAXP];
    __shared__ int pcnt;
    __shared__ int widx[ROWS];
    __shared__ float wsum[4];

    const int tid = threadIdx.x;
    const int wave = tid >> 6;
    const int lane = tid & 63;
    const int quad = lane >> 4;
    const int col  = lane & 15;
    const int rowBase = blockIdx.x * ROWS;
    const float* xblk = x + (size_t)rowBase * D;

    if (tid < ROWS) { rowMinU[tid] = 0xFFFFFFFFu; rowBest[tid] = ~0ull; ccnt[tid] = 0; }
    if (tid == 0) pcnt = 0;

    // ---- stage x -> fp32 LDS once (single HBM pass over x; no conversion here) ----
#pragma unroll
    for (int it = 0; it < ROWS * D / 4 / 256; ++it) {   // 8 iters: 2048 float4
        int e = tid + it * 256;
        int r = e >> 6;
        int s = e & 63;
        float4 v = *(const float4*)&xblk[r * D + s * 4];
        *(float4*)&xs[r * D + XSLOT(r, s) * 4] = v;
    }
    __syncthreads();

    // ---- coarse bf16 MFMA search: fp32 LDS -> bf16 fragments on the fly ----
    for (int g = 0; g < NG; ++g) {
        floatx4 acc[2][4];
#pragma unroll
        for (int i = 0; i < 2; ++i)
#pragma unroll
            for (int j = 0; j < 4; ++j) acc[i][j] = (floatx4){0.f, 0.f, 0.f, 0.f};

#pragma unroll
        for (int kb = 0; kb < NKB; ++kb) {
            bf16x8 af[2], bfr[4];
#pragma unroll
            for (int i = 0; i < 2; ++i) {
                int r = i * 16 + col;
                int s0 = kb * 8 + quad * 2;            // even -> s0+1 flips low bit only
                int slot0 = XSLOT(r, s0);
                float4 a = *(const float4*)&xs[r * D + slot0 * 4];
                float4 b = *(const float4*)&xs[r * D + (slot0 ^ 1) * 4];
                af[i] = pack8(a, b);
            }
#pragma unroll
            for (int j = 0; j < 4; ++j) {
                int S = ((g * 8 + kb) * 4 + wave) * 4 + j;
                bfr[j] = *(const bf16x8*)(cbf + (size_t)S * 512 + lane * 8);
            }
#pragma unroll
            for (int j = 0; j < 4; ++j)
#pragma unroll
                for (int i = 0; i < 2; ++i)
                    acc[i][j] = __builtin_amdgcn_mfma_f32_16x16x32_bf16(af[i], bfr[j], acc[i][j], 0, 0, 0);
        }

        // ---- group epilogue: running per-row min, then candidate collect ----
        const int cbase = g * GROUPC + wave * 64;
        float cn[4];
#pragma unroll
        for (int j = 0; j < 4; ++j) cn[j] = cnorm[cbase + j * 16 + col];

#pragma unroll
        for (int i = 0; i < 2; ++i)
#pragma unroll
            for (int reg = 0; reg < 4; ++reg) {
                float v = cn[0] - 2.f * acc[i][0][reg];
#pragma unroll
                for (int j = 1; j < 4; ++j)
                    v = fminf(v, cn[j] - 2.f * acc[i][j][reg]);
#pragma unroll
                for (int off = 1; off < 16; off <<= 1)
                    v = fminf(v, __shfl_xor(v, off, 64));
                if (col == 0)
                    atomicMin(&rowMinU[i * 16 + quad * 4 + reg], fkey(v));
            }
        __syncthreads();   // bound includes this group before collect
#pragma unroll
        for (int i = 0; i < 2; ++i)
#pragma unroll
            for (int reg = 0; reg < 4; ++reg) {
                int row = i * 16 + quad * 4 + reg;
                float lim = unfkey(rowMinU[row]) + MARGIN;
#pragma unroll
                for (int j = 0; j < 4; ++j) {
                    float d2 = cn[j] - 2.f * acc[i][j][reg];
                    if (d2 < lim) {
                        int slot = atomicAdd(&ccnt[row], 1);
                        if (slot < MAXC) cand[row][slot] = cbase + j * 16 + col;
                    }
                }
            }
    }
    __syncthreads();

    // ---- build compact (row,code) pair list ----
    if (tid < ROWS) {
        int m = ccnt[tid]; if (m > MAXC) m = MAXC;
        for (int c = 0; c < m; ++c) {
            int p = atomicAdd(&pcnt, 1);
            pairs[p] = (tid << 10) | cand[tid][c];   // can't exceed MAXP by construction
        }
    }
    __syncthreads();
    const int np = pcnt;

    // ---- exact fp32 rescore: x from LDS, cb from L2 ----
    const int team = wave * 4 + quad;
    for (int p = team; p < np; p += 16) {
        int pr = pairs[p];
        int row = pr >> 10, code = pr & 1023;
        const float* er = cb + (size_t)code * D + col * 16;
        float s = 0.f;
#pragma unroll
        for (int q = 0; q < 4; ++q) {
            int sg = col * 4 + q;
            float4 a = *(const float4*)&xs[row * D + XSLOT(row, sg) * 4];
            float4 b = *(const float4*)(er + q * 4);
            s += a.x * b.x + a.y * b.y + a.z * b.z + a.w * b.w;
        }
#pragma unroll
        for (int off = 1; off < 16; off <<= 1) s += __shfl_xor(s, off, 64);
        if (col == 0) {
            float dist = cnorm[code] - 2.f * s;
            unsigned long long pack = ((unsigned long long)fkey(dist) << 32) | (unsigned int)code;
            atomicMin(&rowBest[row], pack);
        }
    }

    // ---- overflow fallback (~never): exact full scan for rows with ccnt > MAXC ----
    for (int rr = 0; rr < ROWS / 4; ++rr) {
        const int rl = wave * (ROWS / 4) + rr;
        if (ccnt[rl] > MAXC) {
            float best = 3.4e38f;
            int bi = 0x7fffffff;
            for (int c = lane; c < K; c += 64) {
                float p = 0.f;
                for (int k = 0; k < D; ++k) {
                    int sg = k >> 2;
                    p += xs[rl * D + XSLOT(rl, sg) * 4 + (k & 3)] * cb[(size_t)c * D + k];
                }
                float dist = cnorm[c] - 2.f * p;
                if (dist < best || (dist == best && c < bi)) { best = dist; bi = c; }
            }
#pragma unroll
            for (int off = 1; off < 64; off <<= 1) {
                float ob = __shfl_xor(best, off, 64);
                int oi = __shfl_xor(bi, off, 64);
                if (ob < best || (ob == best && oi < bi)) { best = ob; bi = oi; }
            }
            if (lane == 0)
                atomicMin(&rowBest[rl], ((unsigned long long)fkey(best) << 32) | (unsigned int)bi);
        }
    }
    __syncthreads();
    if (tid < ROWS) widx[tid] = (int)(rowBest[tid] & 0xffffffffu);
    __syncthreads();

    // ---- gather + loss: q from L2 codebook, x from LDS (zero HBM x re-read) ----
    float part = 0.f;
#pragma unroll
    for (int it = 0; it < ROWS * D / 4 / 256; ++it) {   // 8 iters
        int e4 = tid + it * 256;
        int r = e4 >> 6, s = e4 & 63;
        float4 q = *(const float4*)&cb[(size_t)widx[r] * D + s * 4];
        float4 xv = *(const float4*)&xs[r * D + XSLOT(r, s) * 4];
        *(float4*)&out[(size_t)rowBase * D + r * D + s * 4] = q;
        float a = q.x - xv.x, b = q.y - xv.y, c2 = q.z - xv.z, d2 = q.w - xv.w;
        part += a * a + b * b + c2 * c2 + d2 * d2;
    }
#pragma unroll
    for (int off = 32; off > 0; off >>= 1) part += __shfl_down(part, off, 64);
    if (lane == 0) wsum[wave] = part;
    __syncthreads();
    if (tid == 0) atomicAdd(lossAcc, wsum[0] + wsum[1] + wsum[2] + wsum[3]);
}

__global__ void vq_final_kernel(const float* __restrict__ lossAcc, float* __restrict__ outLoss) {
    *outLoss = 1.25f * (*lossAcc) / 16777216.f;  // q_latent + 0.25*e_latent
}

extern "C" void kernel_launch(void* const* d_in, const int* in_sizes, int n_in,
                              void* d_out, int out_size, void* d_ws, size_t ws_size,
                              hipStream_t stream) {
    const float* x  = (const float*)d_in[0];
    const float* cb = (const float*)d_in[1];
    float* out = (float*)d_out;

    float* cnorm = (float*)d_ws;                                  // 4KB
    float* lossAcc = cnorm + K;                                   // @4KB
    unsigned short* cbf = (unsigned short*)((char*)d_ws + 8192);  // 512KB

    vq_prep<<<K, 64, 0, stream>>>(cb, cnorm, cbf, lossAcc);
    vq_fused<<<NVEC / ROWS, 256, 0, stream>>>(x, cb, cbf, cnorm, lossAcc, out);
    vq_final_kernel<<<1, 1, 0, stream>>>(lossAcc, out + (size_t)NVEC * D);
}

// Round 7
// 210.802 us; speedup vs baseline: 1.3756x; 1.0044x over previous
//
#include <hip/hip_runtime.h>

#define D 256
#define K 1024
#define NVEC 65536
#define ROWS 32       // rows per block
#define GROUPC 256    // codes per group (per-wave slice = 64)
#define NG (K / GROUPC)
#define NKB (D / 32)  // 8 k-steps of 32
#define MARGIN 0.5f   // ~7 sigma of bf16 coarse-distance error
#define MAXC 12
#define MAXP (ROWS * MAXC)

typedef __attribute__((ext_vector_type(8))) __bf16 bf16x8;
typedef __attribute__((ext_vector_type(4))) float floatx4;

__device__ inline unsigned short f2bf(float f) {  // RNE fp32->bf16
    unsigned int u = __float_as_uint(f);
    unsigned int r = u + 0x7fffu + ((u >> 16) & 1u);
    return (unsigned short)(r >> 16);
}
__device__ inline unsigned int fkey(float f) {    // order-preserving float->uint
    unsigned int b = __float_as_uint(f);
    return (b & 0x80000000u) ? ~b : (b | 0x80000000u);
}
__device__ inline float unfkey(unsigned int k) {
    unsigned int b = (k & 0x80000000u) ? (k & 0x7fffffffu) : ~k;
    return __uint_as_float(b);
}

// fp32 x LDS swizzle: row r has 64 segs of 16B (4 floats); seg s stored at
// slot = (s & 32) | ((s & 31) ^ (r & 31)).  Bijective per row.  All fp32
// readers use patterns where slot&7 varies with lane (2 lanes/bank-group).
#define XSLOT(r, s) (((s) & 32) | (((s) & 31) ^ ((r) & 31)))

// ws: cnorm fp32 [0,4KB) | lossAcc @4KB | cbf bf16 (B-fragment order) @8KB (512KB)

// cbf layout: code c -> g=c>>8, w=(c>>6)&3, j=(c>>4)&3, col=c&15 ; k -> kb=k>>5,
// quad=(k>>3)&3, h=k&7.  16B seg index = S*64 + quad*16+col, S=((g*8+kb)*4+w)*4+j.
// In the k-loop, wave w / group g / kb / j reads seg S*64+lane => base + lane*16B.
__global__ void vq_prep(const float* __restrict__ cb, float* __restrict__ cnorm,
                        unsigned short* __restrict__ cbf, float* __restrict__ lossAcc) {
    const int c = blockIdx.x;
    const int l = threadIdx.x;
    float4 v = *(const float4*)&cb[c * D + l * 4];
    float s = v.x * v.x + v.y * v.y + v.z * v.z + v.w * v.w;
#pragma unroll
    for (int off = 32; off > 0; off >>= 1) s += __shfl_down(s, off, 64);
    if (l == 0) cnorm[c] = s;
    const int g = c >> 8, w = (c >> 6) & 3, j = (c >> 4) & 3, col = c & 15;
    const int kb = l >> 3, quad = (l >> 1) & 3, h = (l & 1) * 4;
    const int S = ((g * 8 + kb) * 4 + w) * 4 + j;
    *(ushort4*)(cbf + (size_t)S * 512 + (quad * 16 + col) * 8 + h) =
        make_ushort4(f2bf(v.x), f2bf(v.y), f2bf(v.z), f2bf(v.w));
    if (c == 0 && l == 0) *lossAcc = 0.f;
}

__global__ __launch_bounds__(256, 4) void vq_fused(
        const float* __restrict__ x, const float* __restrict__ cb,
        const unsigned short* __restrict__ cbf, const float* __restrict__ cnorm,
        float* __restrict__ lossAcc, float* __restrict__ out)
{
    __shared__ __align__(16) float xsf[ROWS * D];            // 32 KB fp32 (rescore/gather)
    __shared__ __align__(16) unsigned short xsb[ROWS * D];   // 16 KB bf16 (MFMA af), round-5 swizzle
    __shared__ unsigned int rowMinU[ROWS];
    __shared__ unsigned long long rowBest[ROWS];
    __shared__ int ccnt[ROWS];
    __shared__ int cand[ROWS][MAXC];
    __shared__ int pairs[MAXP];
    __shared__ int pcnt;
    __shared__ int widx[ROWS];
    __shared__ float wsum[4];

    const int tid = threadIdx.x;
    const int wave = tid >> 6;
    const int lane = tid & 63;
    const int quad = lane >> 4;
    const int col  = lane & 15;
    const int rowBase = blockIdx.x * ROWS;
    const float* xblk = x + (size_t)rowBase * D;

    if (tid < ROWS) { rowMinU[tid] = 0xFFFFFFFFu; rowBest[tid] = ~0ull; ccnt[tid] = 0; }
    if (tid == 0) pcnt = 0;

    // ---- stage x once: fp32 copy (swizzled) + bf16 copy (converted ONCE here) ----
#pragma unroll
    for (int it = 0; it < ROWS * D / 4 / 256; ++it) {   // 8 iters: 2048 float4
        int e = tid + it * 256;
        int r = e >> 6;
        int s = e & 63;
        float4 v = *(const float4*)&xblk[r * D + s * 4];
        *(float4*)&xsf[r * D + XSLOT(r, s) * 4] = v;
        int slot = (s >> 1) ^ (r & 31);                 // round-5 bf16 seg swizzle
        *(ushort4*)&xsb[r * D + slot * 8 + (s & 1) * 4] =
            make_ushort4(f2bf(v.x), f2bf(v.y), f2bf(v.z), f2bf(v.w));
    }
    __syncthreads();

    // ---- coarse bf16 MFMA search: af via single ds_read_b128 (proven pattern) ----
    for (int g = 0; g < NG; ++g) {
        floatx4 acc[2][4];
#pragma unroll
        for (int i = 0; i < 2; ++i)
#pragma unroll
            for (int j = 0; j < 4; ++j) acc[i][j] = (floatx4){0.f, 0.f, 0.f, 0.f};

#pragma unroll
        for (int kb = 0; kb < NKB; ++kb) {
            bf16x8 af[2], bfr[4];
#pragma unroll
            for (int i = 0; i < 2; ++i) {
                int r = i * 16 + col;
                int slot = (kb * 4 + quad) ^ (r & 31);
                af[i] = *(const bf16x8*)&xsb[r * D + slot * 8];
            }
#pragma unroll
            for (int j = 0; j < 4; ++j) {
                int S = ((g * 8 + kb) * 4 + wave) * 4 + j;
                bfr[j] = *(const bf16x8*)(cbf + (size_t)S * 512 + lane * 8);
            }
#pragma unroll
            for (int j = 0; j < 4; ++j)
#pragma unroll
                for (int i = 0; i < 2; ++i)
                    acc[i][j] = __builtin_amdgcn_mfma_f32_16x16x32_bf16(af[i], bfr[j], acc[i][j], 0, 0, 0);
        }

        // ---- group epilogue: running per-row min, then candidate collect ----
        const int cbase = g * GROUPC + wave * 64;
        float cn[4];
#pragma unroll
        for (int j = 0; j < 4; ++j) cn[j] = cnorm[cbase + j * 16 + col];

#pragma unroll
        for (int i = 0; i < 2; ++i)
#pragma unroll
            for (int reg = 0; reg < 4; ++reg) {
                float v = cn[0] - 2.f * acc[i][0][reg];
#pragma unroll
                for (int j = 1; j < 4; ++j)
                    v = fminf(v, cn[j] - 2.f * acc[i][j][reg]);
#pragma unroll
                for (int off = 1; off < 16; off <<= 1)
                    v = fminf(v, __shfl_xor(v, off, 64));
                if (col == 0)
                    atomicMin(&rowMinU[i * 16 + quad * 4 + reg], fkey(v));
            }
        __syncthreads();   // bound includes this group before collect
#pragma unroll
        for (int i = 0; i < 2; ++i)
#pragma unroll
            for (int reg = 0; reg < 4; ++reg) {
                int row = i * 16 + quad * 4 + reg;
                float lim = unfkey(rowMinU[row]) + MARGIN;
#pragma unroll
                for (int j = 0; j < 4; ++j) {
                    float d2 = cn[j] - 2.f * acc[i][j][reg];
                    if (d2 < lim) {
                        int slot = atomicAdd(&ccnt[row], 1);
                        if (slot < MAXC) cand[row][slot] = cbase + j * 16 + col;
                    }
                }
            }
    }
    __syncthreads();

    // ---- build compact (row,code) pair list ----
    if (tid < ROWS) {
        int m = ccnt[tid]; if (m > MAXC) m = MAXC;
        for (int c = 0; c < m; ++c) {
            int p = atomicAdd(&pcnt, 1);
            pairs[p] = (tid << 10) | cand[tid][c];   // can't exceed MAXP by construction
        }
    }
    __syncthreads();
    const int np = pcnt;

    // ---- exact fp32 rescore: x from LDS (sg = q*16+col -> 2-way banks), cb from L2 ----
    const int team = wave * 4 + quad;
    for (int p = team; p < np; p += 16) {
        int pr = pairs[p];
        int row = pr >> 10, code = pr & 1023;
        const float* er = cb + (size_t)code * D;
        float s = 0.f;
#pragma unroll
        for (int q = 0; q < 4; ++q) {
            int sg = q * 16 + col;
            float4 a = *(const float4*)&xsf[row * D + XSLOT(row, sg) * 4];
            float4 b = *(const float4*)(er + sg * 4);
            s += a.x * b.x + a.y * b.y + a.z * b.z + a.w * b.w;
        }
#pragma unroll
        for (int off = 1; off < 16; off <<= 1) s += __shfl_xor(s, off, 64);
        if (col == 0) {
            float dist = cnorm[code] - 2.f * s;
            unsigned long long pack = ((unsigned long long)fkey(dist) << 32) | (unsigned int)code;
            atomicMin(&rowBest[row], pack);
        }
    }

    // ---- overflow fallback (~never): exact full scan for rows with ccnt > MAXC ----
    for (int rr = 0; rr < ROWS / 4; ++rr) {
        const int rl = wave * (ROWS / 4) + rr;
        if (ccnt[rl] > MAXC) {
            float best = 3.4e38f;
            int bi = 0x7fffffff;
            for (int c = lane; c < K; c += 64) {
                float p = 0.f;
                for (int k = 0; k < D; ++k) {
                    int sg = k >> 2;
                    p += xsf[rl * D + XSLOT(rl, sg) * 4 + (k & 3)] * cb[(size_t)c * D + k];
                }
                float dist = cnorm[c] - 2.f * p;
                if (dist < best || (dist == best && c < bi)) { best = dist; bi = c; }
            }
#pragma unroll
            for (int off = 1; off < 64; off <<= 1) {
                float ob = __shfl_xor(best, off, 64);
                int oi = __shfl_xor(bi, off, 64);
                if (ob < best || (ob == best && oi < bi)) { best = ob; bi = oi; }
            }
            if (lane == 0)
                atomicMin(&rowBest[rl], ((unsigned long long)fkey(best) << 32) | (unsigned int)bi);
        }
    }
    __syncthreads();
    if (tid < ROWS) widx[tid] = (int)(rowBest[tid] & 0xffffffffu);
    __syncthreads();

    // ---- gather + loss: q from L2 codebook, x from fp32 LDS (zero HBM x re-read) ----
    float part = 0.f;
#pragma unroll
    for (int it = 0; it < ROWS * D / 4 / 256; ++it) {   // 8 iters
        int e4 = tid + it * 256;
        int r = e4 >> 6, s = e4 & 63;
        float4 q = *(const float4*)&cb[(size_t)widx[r] * D + s * 4];
        float4 xv = *(const float4*)&xsf[r * D + XSLOT(r, s) * 4];
        *(float4*)&out[(size_t)rowBase * D + r * D + s * 4] = q;
        float a = q.x - xv.x, b = q.y - xv.y, c2 = q.z - xv.z, d2 = q.w - xv.w;
        part += a * a + b * b + c2 * c2 + d2 * d2;
    }
#pragma unroll
    for (int off = 32; off > 0; off >>= 1) part += __shfl_down(part, off, 64);
    if (lane == 0) wsum[wave] = part;
    __syncthreads();
    if (tid == 0) atomicAdd(lossAcc, wsum[0] + wsum[1] + wsum[2] + wsum[3]);
}

__global__ void vq_final_kernel(const float* __restrict__ lossAcc, float* __restrict__ outLoss) {
    *outLoss = 1.25f * (*lossAcc) / 16777216.f;  // q_latent + 0.25*e_latent
}

extern "C" void kernel_launch(void* const* d_in, const int* in_sizes, int n_in,
                              void* d_out, int out_size, void* d_ws, size_t ws_size,
                              hipStream_t stream) {
    const float* x  = (const float*)d_in[0];
    const float* cb = (const float*)d_in[1];
    float* out = (float*)d_out;

    float* cnorm = (float*)d_ws;                                  // 4KB
    float* lossAcc = cnorm + K;                                   // @4KB
    unsigned short* cbf = (unsigned short*)((char*)d_ws + 8192);  // 512KB

    vq_prep<<<K, 64, 0, stream>>>(cb, cnorm, cbf, lossAcc);
    vq_fused<<<NVEC / ROWS, 256, 0, stream>>>(x, cb, cbf, cnorm, lossAcc, out);
    vq_final_kernel<<<1, 1, 0, stream>>>(lossAcc, out + (size_t)NVEC * D);
}

// Round 8
// 195.911 us; speedup vs baseline: 1.4802x; 1.0760x over previous
//
#include <hip/hip_runtime.h>

#define D 256
#define K 1024
#define NVEC 65536
#define ROWS 32       // rows per block
#define GROUPC 256    // codes per group (per-wave slice = 64)
#define NG (K / GROUPC)
#define NKB (D / 32)  // 8 k-steps of 32
#define MARGIN 0.5f   // ~7 sigma of bf16 coarse-distance error
#define MAXC 12
#define MAXP (ROWS * MAXC)

typedef __attribute__((ext_vector_type(8))) __bf16 bf16x8;
typedef __attribute__((ext_vector_type(4))) float floatx4;

__device__ inline unsigned short f2bf(float f) {  // RNE fp32->bf16
    unsigned int u = __float_as_uint(f);
    unsigned int r = u + 0x7fffu + ((u >> 16) & 1u);
    return (unsigned short)(r >> 16);
}
__device__ inline unsigned int fkey(float f) {    // order-preserving float->uint
    unsigned int b = __float_as_uint(f);
    return (b & 0x80000000u) ? ~b : (b | 0x80000000u);
}
__device__ inline float unfkey(unsigned int k) {
    unsigned int b = (k & 0x80000000u) ? (k & 0x7fffffffu) : ~k;
    return __uint_as_float(b);
}

// fp32 x LDS swizzle: row r has 64 segs of 16B (4 floats); seg s stored at
// slot = (s & 32) | ((s & 31) ^ (r & 31)).  Bijective per row.  All fp32
// readers use patterns where slot&7 varies with lane (2 lanes/bank-group).
#define XSLOT(r, s) (((s) & 32) | (((s) & 31) ^ ((r) & 31)))

// ws: cnorm fp32 [0,4KB) | lossAcc @4KB | cbf bf16 (B-fragment order) @8KB (512KB)

// cbf layout: code c -> g=c>>8, w=(c>>6)&3, j=(c>>4)&3, col=c&15 ; k -> kb=k>>5,
// quad=(k>>3)&3, h=k&7.  16B seg index = S*64 + quad*16+col, S=((g*8+kb)*4+w)*4+j.
// In the k-loop, wave w / group g / kb / j reads seg S*64+lane => base + lane*16B.
__global__ void vq_prep(const float* __restrict__ cb, float* __restrict__ cnorm,
                        unsigned short* __restrict__ cbf, float* __restrict__ lossAcc) {
    const int c = blockIdx.x;
    const int l = threadIdx.x;
    float4 v = *(const float4*)&cb[c * D + l * 4];
    float s = v.x * v.x + v.y * v.y + v.z * v.z + v.w * v.w;
#pragma unroll
    for (int off = 32; off > 0; off >>= 1) s += __shfl_down(s, off, 64);
    if (l == 0) cnorm[c] = s;
    const int g = c >> 8, w = (c >> 6) & 3, j = (c >> 4) & 3, col = c & 15;
    const int kb = l >> 3, quad = (l >> 1) & 3, h = (l & 1) * 4;
    const int S = ((g * 8 + kb) * 4 + w) * 4 + j;
    *(ushort4*)(cbf + (size_t)S * 512 + (quad * 16 + col) * 8 + h) =
        make_ushort4(f2bf(v.x), f2bf(v.y), f2bf(v.z), f2bf(v.w));
    if (c == 0 && l == 0) *lossAcc = 0.f;
}

// LDS overlay: coarse phase uses xbuf as bf16 [ROWS*D] (16 KB, round-5 swizzle);
// after the coarse barrier, x is re-staged from global as fp32 [ROWS*D] (32 KB,
// XSLOT swizzle) into the SAME buffer for rescore/fallback/gather.  Phases are
// disjoint; total LDS ~37 KB -> 4 blocks/CU (vs 53 KB -> 3).
__global__ __launch_bounds__(256, 4) void vq_fused(
        const float* __restrict__ x, const float* __restrict__ cb,
        const unsigned short* __restrict__ cbf, const float* __restrict__ cnorm,
        float* __restrict__ lossAcc, float* __restrict__ out)
{
    __shared__ __align__(16) unsigned char xbuf[ROWS * D * 4];   // 32 KB union
    __shared__ unsigned int rowMinU[ROWS];
    __shared__ unsigned long long rowBest[ROWS];
    __shared__ int ccnt[ROWS];
    __shared__ int cand[ROWS][MAXC];
    __shared__ int pairs[MAXP];
    __shared__ int pcnt;
    __shared__ int widx[ROWS];
    __shared__ float wsum[4];

    unsigned short* xsb = (unsigned short*)xbuf;   // bf16 view (first 16 KB)
    float* xsf = (float*)xbuf;                     // fp32 view (all 32 KB)

    const int tid = threadIdx.x;
    const int wave = tid >> 6;
    const int lane = tid & 63;
    const int quad = lane >> 4;
    const int col  = lane & 15;
    const int rowBase = blockIdx.x * ROWS;
    const float* xblk = x + (size_t)rowBase * D;

    if (tid < ROWS) { rowMinU[tid] = 0xFFFFFFFFu; rowBest[tid] = ~0ull; ccnt[tid] = 0; }
    if (tid == 0) pcnt = 0;

    // ---- stage x -> bf16 LDS (converted once; fp32 copy comes later via re-stage) ----
#pragma unroll
    for (int it = 0; it < ROWS * D / 4 / 256; ++it) {   // 8 iters: 2048 float4
        int e = tid + it * 256;
        int r = e >> 6;
        int s = e & 63;
        float4 v = *(const float4*)&xblk[r * D + s * 4];
        int slot = (s >> 1) ^ (r & 31);                 // round-5 bf16 seg swizzle
        *(ushort4*)&xsb[r * D + slot * 8 + (s & 1) * 4] =
            make_ushort4(f2bf(v.x), f2bf(v.y), f2bf(v.z), f2bf(v.w));
    }
    __syncthreads();

    // ---- coarse bf16 MFMA search: af via single ds_read_b128 (proven pattern) ----
    for (int g = 0; g < NG; ++g) {
        floatx4 acc[2][4];
#pragma unroll
        for (int i = 0; i < 2; ++i)
#pragma unroll
            for (int j = 0; j < 4; ++j) acc[i][j] = (floatx4){0.f, 0.f, 0.f, 0.f};

#pragma unroll
        for (int kb = 0; kb < NKB; ++kb) {
            bf16x8 af[2], bfr[4];
#pragma unroll
            for (int i = 0; i < 2; ++i) {
                int r = i * 16 + col;
                int slot = (kb * 4 + quad) ^ (r & 31);
                af[i] = *(const bf16x8*)&xsb[r * D + slot * 8];
            }
#pragma unroll
            for (int j = 0; j < 4; ++j) {
                int S = ((g * 8 + kb) * 4 + wave) * 4 + j;
                bfr[j] = *(const bf16x8*)(cbf + (size_t)S * 512 + lane * 8);
            }
#pragma unroll
            for (int j = 0; j < 4; ++j)
#pragma unroll
                for (int i = 0; i < 2; ++i)
                    acc[i][j] = __builtin_amdgcn_mfma_f32_16x16x32_bf16(af[i], bfr[j], acc[i][j], 0, 0, 0);
        }

        // ---- group epilogue: running per-row min, then candidate collect ----
        const int cbase = g * GROUPC + wave * 64;
        float cn[4];
#pragma unroll
        for (int j = 0; j < 4; ++j) cn[j] = cnorm[cbase + j * 16 + col];

#pragma unroll
        for (int i = 0; i < 2; ++i)
#pragma unroll
            for (int reg = 0; reg < 4; ++reg) {
                float v = cn[0] - 2.f * acc[i][0][reg];
#pragma unroll
                for (int j = 1; j < 4; ++j)
                    v = fminf(v, cn[j] - 2.f * acc[i][j][reg]);
#pragma unroll
                for (int off = 1; off < 16; off <<= 1)
                    v = fminf(v, __shfl_xor(v, off, 64));
                if (col == 0)
                    atomicMin(&rowMinU[i * 16 + quad * 4 + reg], fkey(v));
            }
        __syncthreads();   // bound includes this group before collect
#pragma unroll
        for (int i = 0; i < 2; ++i)
#pragma unroll
            for (int reg = 0; reg < 4; ++reg) {
                int row = i * 16 + quad * 4 + reg;
                float lim = unfkey(rowMinU[row]) + MARGIN;
#pragma unroll
                for (int j = 0; j < 4; ++j) {
                    float d2 = cn[j] - 2.f * acc[i][j][reg];
                    if (d2 < lim) {
                        int slot = atomicAdd(&ccnt[row], 1);
                        if (slot < MAXC) cand[row][slot] = cbase + j * 16 + col;
                    }
                }
            }
    }
    __syncthreads();   // coarse done: xsb dead, safe to overwrite with fp32 x

    // ---- re-stage x -> fp32 LDS (coalesced burst; overlaps pair-building) ----
#pragma unroll
    for (int it = 0; it < ROWS * D / 4 / 256; ++it) {   // 8 iters
        int e = tid + it * 256;
        int r = e >> 6;
        int s = e & 63;
        float4 v = *(const float4*)&xblk[r * D + s * 4];
        *(float4*)&xsf[r * D + XSLOT(r, s) * 4] = v;
    }

    // ---- build compact (row,code) pair list ----
    if (tid < ROWS) {
        int m = ccnt[tid]; if (m > MAXC) m = MAXC;
        for (int c = 0; c < m; ++c) {
            int p = atomicAdd(&pcnt, 1);
            pairs[p] = (tid << 10) | cand[tid][c];   // can't exceed MAXP by construction
        }
    }
    __syncthreads();   // fp32 x staged + pair list ready
    const int np = pcnt;

    // ---- exact fp32 rescore: x from LDS (sg = q*16+col -> 2-way banks), cb from L2 ----
    const int team = wave * 4 + quad;
    for (int p = team; p < np; p += 16) {
        int pr = pairs[p];
        int row = pr >> 10, code = pr & 1023;
        const float* er = cb + (size_t)code * D;
        float s = 0.f;
#pragma unroll
        for (int q = 0; q < 4; ++q) {
            int sg = q * 16 + col;
            float4 a = *(const float4*)&xsf[row * D + XSLOT(row, sg) * 4];
            float4 b = *(const float4*)(er + sg * 4);
            s += a.x * b.x + a.y * b.y + a.z * b.z + a.w * b.w;
        }
#pragma unroll
        for (int off = 1; off < 16; off <<= 1) s += __shfl_xor(s, off, 64);
        if (col == 0) {
            float dist = cnorm[code] - 2.f * s;
            unsigned long long pack = ((unsigned long long)fkey(dist) << 32) | (unsigned int)code;
            atomicMin(&rowBest[row], pack);
        }
    }

    // ---- overflow fallback (~never): exact full scan for rows with ccnt > MAXC ----
    for (int rr = 0; rr < ROWS / 4; ++rr) {
        const int rl = wave * (ROWS / 4) + rr;
        if (ccnt[rl] > MAXC) {
            float best = 3.4e38f;
            int bi = 0x7fffffff;
            for (int c = lane; c < K; c += 64) {
                float p = 0.f;
                for (int k = 0; k < D; ++k) {
                    int sg = k >> 2;
                    p += xsf[rl * D + XSLOT(rl, sg) * 4 + (k & 3)] * cb[(size_t)c * D + k];
                }
                float dist = cnorm[c] - 2.f * p;
                if (dist < best || (dist == best && c < bi)) { best = dist; bi = c; }
            }
#pragma unroll
            for (int off = 1; off < 64; off <<= 1) {
                float ob = __shfl_xor(best, off, 64);
                int oi = __shfl_xor(bi, off, 64);
                if (ob < best || (ob == best && oi < bi)) { best = ob; bi = oi; }
            }
            if (lane == 0)
                atomicMin(&rowBest[rl], ((unsigned long long)fkey(best) << 32) | (unsigned int)bi);
        }
    }
    __syncthreads();
    if (tid < ROWS) widx[tid] = (int)(rowBest[tid] & 0xffffffffu);
    __syncthreads();

    // ---- gather + loss: q from L2 codebook, x from fp32 LDS ----
    float part = 0.f;
#pragma unroll
    for (int it = 0; it < ROWS * D / 4 / 256; ++it) {   // 8 iters
        int e4 = tid + it * 256;
        int r = e4 >> 6, s = e4 & 63;
        float4 q = *(const float4*)&cb[(size_t)widx[r] * D + s * 4];
        float4 xv = *(const float4*)&xsf[r * D + XSLOT(r, s) * 4];
        *(float4*)&out[(size_t)rowBase * D + r * D + s * 4] = q;
        float a = q.x - xv.x, b = q.y - xv.y, c2 = q.z - xv.z, d2 = q.w - xv.w;
        part += a * a + b * b + c2 * c2 + d2 * d2;
    }
#pragma unroll
    for (int off = 32; off > 0; off >>= 1) part += __shfl_down(part, off, 64);
    if (lane == 0) wsum[wave] = part;
    __syncthreads();
    if (tid == 0) atomicAdd(lossAcc, wsum[0] + wsum[1] + wsum[2] + wsum[3]);
}

__global__ void vq_final_kernel(const float* __restrict__ lossAcc, float* __restrict__ outLoss) {
    *outLoss = 1.25f * (*lossAcc) / 16777216.f;  // q_latent + 0.25*e_latent
}

extern "C" void kernel_launch(void* const* d_in, const int* in_sizes, int n_in,
                              void* d_out, int out_size, void* d_ws, size_t ws_size,
                              hipStream_t stream) {
    const float* x  = (const float*)d_in[0];
    const float* cb = (const float*)d_in[1];
    float* out = (float*)d_out;

    float* cnorm = (float*)d_ws;                                  // 4KB
    float* lossAcc = cnorm + K;                                   // @4KB
    unsigned short* cbf = (unsigned short*)((char*)d_ws + 8192);  // 512KB

    vq_prep<<<K, 64, 0, stream>>>(cb, cnorm, cbf, lossAcc);
    vq_fused<<<NVEC / ROWS, 256, 0, stream>>>(x, cb, cbf, cnorm, lossAcc, out);
    vq_final_kernel<<<1, 1, 0, stream>>>(lossAcc, out + (size_t)NVEC * D);
}